// Round 18
// baseline (582.293 us; speedup 1.0000x reference)
//
#include <hip/hip_runtime.h>
#include <hip/hip_cooperative_groups.h>
#include <cstdint>

namespace cg = cooperative_groups;

#define NEG_SLOPE 0.2f
#define EPS 1e-16f
#define BSH 7                  // 128 nodes per bucket/block
#define BNODES (1 << BSH)
#define NBMAX 1024             // supports N <= 131072
#define CAP 2560               // bucket capacity (mean ~1766, +19 sigma)
#define MAXDEG 64              // padded row (Poisson(12.8)+self-loop << 64)
#define ROWP 65                // row stride: (i*65+r)%32 distinct per lane
#define TPB 256                // threads per block
#define BEPT 8                 // edges per thread in P1 (782*256*8 = 1.6M >= Etot)

__device__ __forceinline__ float lrelu(float x) {
    return (x >= 0.f) ? x : NEG_SLOPE * x;
}

// wave-wide sum (P0 consts only), DPP rotate-reduce
template <int CTRL>
__device__ __forceinline__ float dpp_ror_add(float v) {
    int r = __builtin_amdgcn_update_dpp(0, __float_as_int(v), CTRL, 0xf, 0xf, true);
    return v + __int_as_float(r);
}
__device__ __forceinline__ float wave_sum(float v) {
    v = dpp_ror_add<0x121>(v);
    v = dpp_ror_add<0x122>(v);
    v = dpp_ror_add<0x124>(v);
    v = dpp_ror_add<0x128>(v);
    v += __shfl_xor(v, 16);
    v += __shfl_xor(v, 32);
    return v;
}

// ====== single cooperative kernel: P0 init | P1 bucket | P2 L1+node2 | P3 L2 ======
__global__ __launch_bounds__(TPB)
void gat_kernel(const int* __restrict__ src, const int* __restrict__ dst,
                const float2* __restrict__ x,
                const float* __restrict__ W1, const float* __restrict__ as1,
                const float* __restrict__ ad1, const float* __restrict__ b1,
                const float* __restrict__ W2, const float* __restrict__ as2,
                const float* __restrict__ ad2, const float* __restrict__ b2,
                int* __restrict__ gcur, unsigned* __restrict__ bkt,
                float4* __restrict__ pack2, float2* __restrict__ out,
                int N, int E, int Etot, int nbuck) {
    // 33.3 KB union: P1 {cnt|base|pay|rb} / P2-P3 rows
    __shared__ alignas(16) char uls[BNODES * ROWP * 4];
    __shared__ int cur[BNODES];
    __shared__ float4 tab[64];             // {w1a, w1b, b1, w2a}
    __shared__ float w2bL[64];
    __shared__ float4 cbox;                // consts (per-block copy)

    int* rows = (int*)uls;
    int* cnt  = (int*)uls;                              // [0, 4K)
    int* base = (int*)(uls + NBMAX * 4);                // [4K, 8K)
    unsigned* pay = (unsigned*)(uls + NBMAX * 8);       // [8K, 16K)
    unsigned* rb  = (unsigned*)(uls + NBMAX * 8 + TPB * BEPT * 4);  // [16K, 24K)

    cg::grid_group grid = cg::this_grid();
    int b = blockIdx.x, tid = threadIdx.x;
    int nodeBase = b << BSH;

    // ---- P0: per-block init (no separate const kernel) ----
    if (tid == 0) gcur[b] = 0;
    if (tid < BNODES) cur[tid] = 0;
    if (tid < 64) {
        float w0 = W1[2 * tid], w1v = W1[2 * tid + 1];
        tab[tid] = make_float4(w0, w1v, b1[tid], W2[tid]);
        w2bL[tid] = W2[64 + tid];
        float s = as1[tid], d = ad1[tid];
        float c0 = wave_sum(w0 * s);
        float c1 = wave_sum(w1v * s);
        float e0 = wave_sum(w0 * d);
        float e1 = wave_sum(w1v * d);
        if (tid == 0) cbox = make_float4(c0, c1, e0, e1);
    }
    for (int q = tid; q < nbuck; q += TPB) cnt[q] = 0;
    __threadfence();
    grid.sync();

    // ---- P1: bucket partition (rank fused into histogram; LDS staging) ----
    long long blockBase = (long long)b * (TPB * BEPT);
    #pragma unroll
    for (int k = 0; k < BEPT; ++k) {
        int idx = k * TPB + tid;
        long long i = blockBase + idx;
        unsigned rv = 0xFFFFFFFFu;
        if (i < Etot) {
            int s, d;
            if (i < E) { s = src[i]; d = dst[i]; } else { s = d = (int)(i - E); }
            int bk = d >> BSH;
            int rank = atomicAdd(&cnt[bk], 1);          // rank within block
            pay[idx] = ((unsigned)s << BSH) | (unsigned)(d & (BNODES - 1));
            rv = ((unsigned)rank << 10) | (unsigned)bk; // rank<=2047 (11b), bk<1024 (10b)
        }
        rb[idx] = rv;
    }
    __syncthreads();
    for (int q = tid; q < nbuck; q += TPB) {
        int c = cnt[q];
        if (c) base[q] = atomicAdd(gcur + q, c);        // chunk reservation
    }
    __syncthreads();
    #pragma unroll
    for (int k = 0; k < BEPT; ++k) {
        int idx = k * TPB + tid;
        unsigned rv = rb[idx];
        if (rv != 0xFFFFFFFFu) {
            int bk = rv & (NBMAX - 1);
            int pos = base[bk] + (int)(rv >> 10);
            if (pos < CAP) bkt[(size_t)bk * CAP + pos] = pay[idx];  // cached store
        }
    }
    __threadfence();
    grid.sync();
    __threadfence();

    // ---- P2: rebuild rows (LDS) + layer-1 agg + node2 (lane-per-node) ----
    int cnt_b = gcur[b];
    if (cnt_b > CAP) cnt_b = CAP;
    const unsigned* bp = bkt + (size_t)b * CAP;
    for (int k = tid; k < cnt_b; k += TPB) {
        unsigned p = bp[k];
        int ld = p & (BNODES - 1);
        int r = atomicAdd(&cur[ld], 1);
        if (r < MAXDEG) rows[ld * ROWP + r] = (int)(p >> BSH);
    }
    __syncthreads();

    if (tid < BNODES) {
        int n = nodeBase + tid;
        if (n < N) {
            int dg = cur[tid];
            if (dg > MAXDEG) dg = MAXDEG;
            float4 c = cbox;
            float2 xn = x[n];
            float adst_n = fmaf(xn.x, c.z, xn.y * c.w);
            float sp = 0.f, s0 = 0.f, s1 = 0.f;
            for (int r = 0; r < dg; ++r) {
                int s = rows[tid * ROWP + r];           // conflict-free stride 65
                float2 xs = x[s];                       // 8B gather, L2-resident
                float e = lrelu(fmaf(xs.x, c.x, xs.y * c.y) + adst_n);
                float pv = __expf(e);                   // unshifted; shift-invariant
                sp += pv;
                s0 = fmaf(pv, xs.x, s0);
                s1 = fmaf(pv, xs.y, s1);
            }
            float rden = 1.f / (sp + EPS);
            s0 *= rden;
            s1 *= rden;
            float q0 = 0.f, q1 = 0.f;
            #pragma unroll 8
            for (int j = 0; j < 64; ++j) {              // node2: uniform LDS reads
                float4 t = tab[j];
                float hr = fmaxf(fmaf(t.x, s0, t.y * s1) + t.z, 0.f);
                q0 = fmaf(hr, t.w, q0);
                q1 = fmaf(hr, w2bL[j], q1);
            }
            pack2[n] = make_float4(q0, q1,
                                   fmaf(q0, as2[0], q1 * as2[1]),
                                   fmaf(q0, ad2[0], q1 * ad2[1]));
        }
    }
    __threadfence();
    grid.sync();
    __threadfence();

    // ---- P3: layer-2 agg + bias + log_softmax (rows/cur persist in LDS) ----
    if (tid < BNODES) {
        int n = nodeBase + tid;
        if (n < N) {
            int dg = cur[tid];
            if (dg > MAXDEG) dg = MAXDEG;
            float adst_n = ((const float*)(pack2 + n))[3];
            float sp = 0.f, a0 = 0.f, a1 = 0.f;
            for (int r = 0; r < dg; ++r) {
                int s = rows[tid * ROWP + r];
                float4 P = pack2[s];                    // 16B gather, L2-resident
                float pv = __expf(lrelu(P.z + adst_n));
                sp += pv;
                a0 = fmaf(pv, P.x, a0);
                a1 = fmaf(pv, P.y, a1);
            }
            float rd = 1.f / (sp + EPS);
            float v0 = fmaf(a0, rd, b2[0]);
            float v1 = fmaf(a1, rd, b2[1]);
            float mx = fmaxf(v0, v1);
            float lse = mx + logf(__expf(v0 - mx) + __expf(v1 - mx));
            out[n] = make_float2(v0 - lse, v1 - lse);
        }
    }
}

extern "C" void kernel_launch(void* const* d_in, const int* in_sizes, int n_in,
                              void* d_out, int out_size, void* d_ws, size_t ws_size,
                              hipStream_t stream) {
    const int*   src_p  = (const int*)d_in[1];
    const float* x      = (const float*)d_in[0];
    const float* W1     = (const float*)d_in[2];
    const float* att_s1 = (const float*)d_in[3];
    const float* att_d1 = (const float*)d_in[4];
    const float* b1     = (const float*)d_in[5];
    const float* W2     = (const float*)d_in[6];
    const float* att_s2 = (const float*)d_in[7];
    const float* att_d2 = (const float*)d_in[8];
    const float* b2     = (const float*)d_in[9];

    int N     = in_sizes[0] / 2;   // x is [N,2]
    int E     = in_sizes[1] / 2;   // edge_index is [2,E]
    int Etot  = E + N;             // + self loops
    int nbuck = (N + BNODES - 1) >> BSH;   // 782 for N=100k (<= NBMAX)

    const int* src = src_p;
    const int* dst = src_p + E;

    // ---- workspace carve-up (16B aligned) ----
    char* w = (char*)(((uintptr_t)d_ws + 15) & ~(uintptr_t)15);
    int*      gcur  = (int*)w;      w += (size_t)NBMAX * 4;
    unsigned* bkt   = (unsigned*)w; w += (size_t)nbuck * CAP * 4;
    float4*   pack2 = (float4*)w;   w += (size_t)N * 16;

    const float2* x2  = (const float2*)x;
    float2*       out = (float2*)d_out;

    void* args[] = {
        (void*)&src, (void*)&dst, (void*)&x2,
        (void*)&W1, (void*)&att_s1, (void*)&att_d1, (void*)&b1,
        (void*)&W2, (void*)&att_s2, (void*)&att_d2, (void*)&b2,
        (void*)&gcur, (void*)&bkt, (void*)&pack2, (void*)&out,
        (void*)&N, (void*)&E, (void*)&Etot, (void*)&nbuck,
    };
    hipLaunchCooperativeKernel((void*)gat_kernel, dim3(nbuck), dim3(TPB),
                               args, 0, stream);
}

// Round 19
// 53.588 us; speedup vs baseline: 10.8661x; 10.8661x over previous
//
#include <hip/hip_runtime.h>
#include <cstdint>

#define NEG_SLOPE 0.2f
#define EPS 1e-16f
#define BSH 7                  // 128 nodes per bucket
#define BNODES (1 << BSH)
#define NBMAX 1024             // supports N <= 131072
#define CAP 2560               // bucket capacity (mean ~1637 w/o self-loops, +22 sigma)
#define MAXDEG 64              // padded row (Poisson(12.8) << 64; self-loop excluded)
#define ROWP 65                // row stride: (i*65+r)%32 distinct per lane
#define BKT_T 1024             // bucket kernel: threads per block
#define BEPT 8                 // bucket kernel: edges per thread (8192/block)

__device__ __forceinline__ float lrelu(float x) {
    return (x >= 0.f) ? x : NEG_SLOPE * x;
}

// ---- wave-wide sum (const_kernel only), DPP rotate-reduce ----
template <int CTRL>
__device__ __forceinline__ float dpp_ror_add(float v) {
    int r = __builtin_amdgcn_update_dpp(0, __float_as_int(v), CTRL, 0xf, 0xf, true);
    return v + __int_as_float(r);
}
__device__ __forceinline__ float wave_sum(float v) {
    v = dpp_ror_add<0x121>(v);
    v = dpp_ror_add<0x122>(v);
    v = dpp_ror_add<0x124>(v);
    v = dpp_ror_add<0x128>(v);
    v += __shfl_xor(v, 16);
    v += __shfl_xor(v, 32);
    return v;
}

// ---- consts + gcur zeroing (rocclr fill is expensive in-graph) ----
__global__ __launch_bounds__(1024)
void const_kernel(const float* __restrict__ W1,
                  const float* __restrict__ as1,
                  const float* __restrict__ ad1,
                  float4* __restrict__ consts,
                  int* __restrict__ gcur) {
    int tid = threadIdx.x;
    gcur[tid] = 0;                       // NBMAX == 1024
    if (tid < 64) {
        float w0 = W1[2 * tid], w1 = W1[2 * tid + 1];
        float s = as1[tid], d = ad1[tid];
        float c0 = wave_sum(w0 * s);
        float c1 = wave_sum(w1 * s);
        float e0 = wave_sum(w0 * d);
        float e1 = wave_sum(w1 * d);
        if (tid == 0) *consts = make_float4(c0, c1, e0, e1);
    }
}

// ---- pass 1: bucket partition by dst>>7, RANDOM EDGES ONLY ----
// (self-loops handled implicitly in the agg kernels — 7% fewer edges here.)
// Two-read-pass (pass B re-reads dst L2-hot + src cold-stream), no LDS
// payload staging: 2 LDS atomics/edge total. 8192 edges/block doubles the
// per-(block,bucket) run length -> scattered-store writeback ~12.7 -> ~9 MB
// (round-17 analysis: store sectors were the dominant bucket cost).
__global__ __launch_bounds__(BKT_T)
void bucket_kernel(const int* __restrict__ src, const int* __restrict__ dst,
                   int* __restrict__ gcur, unsigned* __restrict__ bkt,
                   int E, int nbuck) {
    __shared__ int cnt[NBMAX];
    __shared__ int base[NBMAX];
    int tid = threadIdx.x;
    long long blockBase = (long long)blockIdx.x * (BKT_T * BEPT);
    cnt[tid] = 0;                        // nbuck <= NBMAX == BKT_T
    __syncthreads();

    // pass A: histogram (no return value needed)
    #pragma unroll
    for (int k = 0; k < BEPT; ++k) {
        long long i = blockBase + k * BKT_T + tid;
        if (i < E) atomicAdd(&cnt[dst[i] >> BSH], 1);
    }
    __syncthreads();
    int c = cnt[tid];
    base[tid] = c ? atomicAdd(gcur + tid, c) : 0;   // chunk reservation
    __syncthreads();
    cnt[tid] = 0;
    __syncthreads();

    // pass B: re-read (dst L2-hot), rank + chunk-merged cached store
    #pragma unroll
    for (int k = 0; k < BEPT; ++k) {
        long long i = blockBase + k * BKT_T + tid;
        if (i < E) {
            int s = src[i], d = dst[i];
            int bk = d >> BSH;
            int r = atomicAdd(&cnt[bk], 1);
            int pos = base[bk] + r;
            if (pos < CAP)
                bkt[(size_t)bk * CAP + pos] =
                    ((unsigned)s << BSH) | (unsigned)(d & (BNODES - 1));
        }
    }
}

// ====== fused distrib + layer-1 agg + node2, LANE-PER-NODE ======
// 128 threads/block, one block per bucket. Build padded rows in LDS (random
// edges only), then lane owns node: self-loop folded in registers, serial
// edge loop, serial 64-feature epilogue over LDS weight table. No cross-lane.
__global__ __launch_bounds__(128)
void agg1t_kernel(const int* __restrict__ gcur, const unsigned* __restrict__ bkt,
                  const float2* __restrict__ x, const float4* __restrict__ consts,
                  const float* __restrict__ W1, const float* __restrict__ b1,
                  const float* __restrict__ W2, const float* __restrict__ as2,
                  const float* __restrict__ ad2, float4* __restrict__ pack2,
                  int N) {
    __shared__ int rows[BNODES * ROWP];    // 33.3 KB
    __shared__ int cur[BNODES];
    __shared__ float4 tab[64];             // {w1a, w1b, b1, w2a}
    __shared__ float w2bL[64];
    int b = blockIdx.x, tid = threadIdx.x;
    int nodeBase = b << BSH;
    cur[tid] = 0;
    if (tid < 64) {
        tab[tid] = make_float4(W1[2 * tid], W1[2 * tid + 1], b1[tid], W2[tid]);
        w2bL[tid] = W2[64 + tid];
    }
    __syncthreads();

    int cnt = gcur[b];
    if (cnt > CAP) cnt = CAP;
    const unsigned* bp = bkt + (size_t)b * CAP;
    for (int k = tid; k < cnt; k += 128) {
        unsigned p = bp[k];                // L2-resident payload
        int ld = p & (BNODES - 1);
        int r = atomicAdd(&cur[ld], 1);
        if (r < MAXDEG) rows[ld * ROWP + r] = (int)(p >> BSH);
    }
    __syncthreads();

    int i = tid;                           // lane-per-node
    int n = nodeBase + i;
    if (n >= N) return;
    int dg = cur[i];
    if (dg > MAXDEG) dg = MAXDEG;
    float4 c = *consts;
    float2 xn = x[n];                      // coalesced 8B
    float asrc_n = fmaf(xn.x, c.x, xn.y * c.y);
    float adst_n = fmaf(xn.x, c.z, xn.y * c.w);

    // self-loop folded in registers
    float pvs = __expf(lrelu(asrc_n + adst_n));
    float sp = pvs, s0 = pvs * xn.x, s1 = pvs * xn.y;
    for (int r = 0; r < dg; ++r) {
        int s = rows[i * ROWP + r];        // conflict-free (stride 65)
        float2 xs = x[s];                  // 8B gather, L2-resident
        float e = lrelu(fmaf(xs.x, c.x, xs.y * c.y) + adst_n);
        float pv = __expf(e);              // unshifted; softmax shift-invariant
        sp += pv;
        s0 = fmaf(pv, xs.x, s0);
        s1 = fmaf(pv, xs.y, s1);
    }
    float rden = 1.f / (sp + EPS);
    s0 *= rden;
    s1 *= rden;

    // node2 epilogue: per-lane serial over 64 features (uniform LDS reads)
    float q0 = 0.f, q1 = 0.f;
    #pragma unroll 8
    for (int j = 0; j < 64; ++j) {
        float4 t = tab[j];
        float hr = fmaxf(fmaf(t.x, s0, t.y * s1) + t.z, 0.f);
        q0 = fmaf(hr, t.w, q0);
        q1 = fmaf(hr, w2bL[j], q1);
    }
    float sa = as2[0], sb = as2[1], da = ad2[0], db = ad2[1];
    pack2[n] = make_float4(q0, q1,
                           fmaf(q0, sa, q1 * sb),
                           fmaf(q0, da, q1 * db));   // coalesced 16B
}

// ====== fused distrib + layer-2 agg + bias + log_softmax, LANE-PER-NODE ====
__global__ __launch_bounds__(128)
void agg2t_kernel(const int* __restrict__ gcur, const unsigned* __restrict__ bkt,
                  const float4* __restrict__ pack2, const float* __restrict__ b2,
                  float2* __restrict__ out, int N) {
    __shared__ int rows[BNODES * ROWP];    // 33.3 KB
    __shared__ int cur[BNODES];
    int b = blockIdx.x, tid = threadIdx.x;
    int nodeBase = b << BSH;
    cur[tid] = 0;
    __syncthreads();

    int cnt = gcur[b];
    if (cnt > CAP) cnt = CAP;
    const unsigned* bp = bkt + (size_t)b * CAP;
    for (int k = tid; k < cnt; k += 128) {
        unsigned p = bp[k];
        int ld = p & (BNODES - 1);
        int r = atomicAdd(&cur[ld], 1);
        if (r < MAXDEG) rows[ld * ROWP + r] = (int)(p >> BSH);
    }
    __syncthreads();

    int i = tid;
    int n = nodeBase + i;
    if (n >= N) return;
    int dg = cur[i];
    if (dg > MAXDEG) dg = MAXDEG;
    float4 Pn = pack2[n];                  // coalesced 16B
    float adst_n = Pn.w;

    // self-loop folded in registers
    float pvs = __expf(lrelu(Pn.z + adst_n));
    float sp = pvs, a0 = pvs * Pn.x, a1 = pvs * Pn.y;
    for (int r = 0; r < dg; ++r) {
        int s = rows[i * ROWP + r];
        float4 P = pack2[s];               // 16B gather, L2-resident
        float pv = __expf(lrelu(P.z + adst_n));
        sp += pv;
        a0 = fmaf(pv, P.x, a0);
        a1 = fmaf(pv, P.y, a1);
    }
    float rd = 1.f / (sp + EPS);
    float v0 = fmaf(a0, rd, b2[0]);
    float v1 = fmaf(a1, rd, b2[1]);
    float mx = fmaxf(v0, v1);
    float lse = mx + logf(__expf(v0 - mx) + __expf(v1 - mx));
    out[n] = make_float2(v0 - lse, v1 - lse);        // coalesced 8B
}

extern "C" void kernel_launch(void* const* d_in, const int* in_sizes, int n_in,
                              void* d_out, int out_size, void* d_ws, size_t ws_size,
                              hipStream_t stream) {
    const float* x      = (const float*)d_in[0];
    const int*   eidx   = (const int*)d_in[1];
    const float* W1     = (const float*)d_in[2];
    const float* att_s1 = (const float*)d_in[3];
    const float* att_d1 = (const float*)d_in[4];
    const float* b1     = (const float*)d_in[5];
    const float* W2     = (const float*)d_in[6];
    const float* att_s2 = (const float*)d_in[7];
    const float* att_d2 = (const float*)d_in[8];
    const float* b2     = (const float*)d_in[9];

    const int N     = in_sizes[0] / 2;   // x is [N,2]
    const int E     = in_sizes[1] / 2;   // edge_index is [2,E]
    const int nbuck = (N + BNODES - 1) >> BSH;   // 782 for N=100k (<= NBMAX)

    const int* src = eidx;
    const int* dst = eidx + E;

    // ---- workspace carve-up (16B aligned) ----
    char* w = (char*)(((uintptr_t)d_ws + 15) & ~(uintptr_t)15);
    int*      gcur   = (int*)w;      w += (size_t)NBMAX * 4;
    unsigned* bkt    = (unsigned*)w; w += (size_t)nbuck * CAP * 4;
    float4*   pack2  = (float4*)w;   w += (size_t)N * 16;
    float4*   consts = (float4*)w;   w += 16;

    // consts + gcur zeroing
    const_kernel<<<dim3(1), dim3(1024), 0, stream>>>(W1, att_s1, att_d1, consts, gcur);

    // ---- pass 1: bucket partition (random edges only, two-read-pass) ----
    int nblocks = (E + BKT_T * BEPT - 1) / (BKT_T * BEPT);
    bucket_kernel<<<dim3(nblocks), dim3(BKT_T), 0, stream>>>(src, dst, gcur, bkt, E, nbuck);

    // ---- fused distrib + layer-1 agg + node2 (lane-per-node, self-implicit) ----
    agg1t_kernel<<<dim3(nbuck), dim3(128), 0, stream>>>(
        gcur, bkt, (const float2*)x, consts, W1, b1, W2, att_s2, att_d2, pack2, N);

    // ---- fused distrib + layer-2 agg + log_softmax (lane-per-node, self-implicit) ----
    agg2t_kernel<<<dim3(nbuck), dim3(128), 0, stream>>>(
        gcur, bkt, pack2, b2, (float2*)d_out, N);
}